// Round 14
// baseline (175.335 us; speedup 1.0000x reference)
//
#include <hip/hip_runtime.h>
#include <math.h>

// Problem constants (ProbAttention: B=4, H=8, L=2048, D=64, factor=5)
#define B_ 4
#define H_ 8
#define L_ 2048
#define D_ 64
#define SK_ 40      // sample_k = 5*ceil(ln(2048)) = 40
#define U_ 40       // u = 40
#define CK 256      // keys per chunk in batched attention
#define NCHUNK (L_ / CK)   // 8
#define QG 8        // queries per attention block
#define NQG (U_ / QG)      // 5
#define CSB 32      // topk blocks (one per bh)
#define SEG2 16     // cumsum segment length
#define NSEG2 (L_ / SEG2)  // 128 segments per head
#define PB 256      // cumsum phase-B blocks riding in the topk launch
#define KCH 4       // K chunks for LDS-staged M kernel
#define KROWS 512   // rows per K chunk (512*256B = 128KB LDS)
#define SORTB 8     // sort blocks in k_setup

// ---------------------------------------------------------------------------
// Kernel 0: setup.
//  blocks 0..7  : chunk-sort idxs into slot-major lists list[c][slot][q]
//                 (ushort, sentinel 0xFFFF). idxs shared across heads ->
//                 2048 sorts total.
//  blocks 8..39 : cumsum PHASE A - per-head exclusive prefix of 16-row
//                 segment sums (moved here from k_mcs).
// ---------------------------------------------------------------------------
__global__ __launch_bounds__(256) void k_setup(
    const int* __restrict__ idxs, const float* __restrict__ V,
    unsigned short* __restrict__ list, float* __restrict__ pfx) {
  if (blockIdx.x < SORTB) {
    int q = blockIdx.x * 256 + threadIdx.x;    // 0..2047
    int c0 = 0, c1 = 0, c2 = 0, c3 = 0;
#pragma unroll
    for (int s = 0; s < SK_; ++s) {
      int ki = idxs[q * SK_ + s];
      int c = ki >> 9;                          // 512-row chunks
      int pos = (c == 0) ? c0 : ((c == 1) ? c1 : ((c == 2) ? c2 : c3));
      list[(c * SK_ + pos) * L_ + q] = (unsigned short)ki;
      c0 += (c == 0); c1 += (c == 1); c2 += (c == 2); c3 += (c == 3);
    }
#pragma unroll
    for (int slot = 0; slot < SK_; ++slot) {
      if (slot >= c0) list[(0 * SK_ + slot) * L_ + q] = 0xFFFFu;
      if (slot >= c1) list[(1 * SK_ + slot) * L_ + q] = 0xFFFFu;
      if (slot >= c2) list[(2 * SK_ + slot) * L_ + q] = 0xFFFFu;
      if (slot >= c3) list[(3 * SK_ + slot) * L_ + q] = 0xFFFFu;
    }
    return;
  }
  // ---- phase A: thread (grp,d); grp covers rows [grp*512,+512) = 32 segs
  __shared__ float wt[4][64];
  int bh = blockIdx.x - SORTB;
  int d = threadIdx.x & 63, grp = threadIdx.x >> 6;
  const float* Vb = V + (size_t)bh * L_ * D_;
  float pres[32];
  float run = 0.f;
#pragma unroll
  for (int i = 0; i < 32; ++i) {
    int base = grp * 512 + i * SEG2;
    float s = 0.f;
    for (int l = 0; l < SEG2; ++l) s += Vb[(size_t)(base + l) * D_ + d];
    pres[i] = run; run += s;
  }
  wt[grp][d] = run;
  __syncthreads();
  float b0 = 0.f;
  for (int g = 0; g < 4; ++g) if (g < grp) b0 += wt[g][d];
#pragma unroll
  for (int i = 0; i < 32; ++i)
    pfx[((size_t)bh * NSEG2 + grp * 32 + i) * D_ + d] = b0 + pres[i];
}

// ---------------------------------------------------------------------------
// Kernel 1 (v10): LDS-staged M scores. Block = (head, 256 queries), 256
// blocks (1/CU). Per K-chunk: stream 128KB L2->LDS (coalesced), then each
// thread computes its query's dots for samples in this chunk, reading rows
// from LDS via the presorted slot lists. XOR swizzle (j4 ^ r&15) spreads
// row-start banks. Replaces the L2 random-gather (measured half-rate).
// ---------------------------------------------------------------------------
__global__ __launch_bounds__(256) void k_compute_M(
    const float* __restrict__ Q, const float* __restrict__ K,
    const unsigned short* __restrict__ list, float* __restrict__ M) {
  extern __shared__ float kch[];   // KROWS x 64 floats, swizzled (128KB)
  int x = blockIdx.x & 7;          // XCD pin: 4 heads per XCD
  int j = blockIdx.x >> 3;         // 0..31
  int bh = (j >> 3) * 8 + x;
  int qblk = j & 7;
  int tid = threadIdx.x;
  int q = qblk * 256 + tid;        // query within head (list index space)

  const float4* qrow = (const float4*)(Q + ((size_t)bh * L_ + q) * D_);
  float4 q4[16];
#pragma unroll
  for (int i = 0; i < 16; ++i) q4[i] = qrow[i];

  float mx = -INFINITY, sm = 0.f;
  for (int c = 0; c < KCH; ++c) {
    __syncthreads();               // prior pass's readers done
    const float4* Ks = (const float4*)(K + ((size_t)bh * L_ + c * KROWS) * D_);
    for (int f = tid; f < KROWS * 16; f += 256) {
      int r = f >> 4, j4 = f & 15;
      float4 v = Ks[f];
      *(float4*)&kch[r * 64 + ((j4 ^ (r & 15)) << 2)] = v;
    }
    __syncthreads();
    for (int slot = 0; slot < SK_; ++slot) {
      unsigned short e = list[(c * SK_ + slot) * L_ + q];  // coalesced
      if (__ballot(e != 0xFFFFu) == 0ull) break;           // wave-uniform
      int local = e & (KROWS - 1);   // sentinel -> row 511 (harmless)
      float a0 = 0.f, a1 = 0.f, a2 = 0.f, a3 = 0.f;
#pragma unroll
      for (int j4 = 0; j4 < 16; ++j4) {
        float4 kv = *(const float4*)&kch[local * 64 + ((j4 ^ (local & 15)) << 2)];
        a0 += q4[j4].x * kv.x; a1 += q4[j4].y * kv.y;
        a2 += q4[j4].z * kv.z; a3 += q4[j4].w * kv.w;
      }
      float dd = (a0 + a1) + (a2 + a3);
      if (e != 0xFFFFu) { mx = fmaxf(mx, dd); sm += dd; }
    }
  }
  M[(size_t)bh * L_ + q] = mx - sm * (1.0f / (float)L_);
}

// ---------------------------------------------------------------------------
// Kernel 2 (v3): heterogeneous launch.
//  blocks 0..31  : top-U_ radix select per head
//  blocks 32..287: cumsum PHASE B (reads pfx, writes out), hides under topk
// ---------------------------------------------------------------------------
__global__ __launch_bounds__(1024) void k_topk(
    const float* __restrict__ M, const float* __restrict__ V,
    const float* __restrict__ pfx, int* __restrict__ Mtop,
    float* __restrict__ out) {
  if (blockIdx.x >= CSB) {
    int bid = blockIdx.x - CSB;    // 0..255
    int bh = bid >> 3, oct = bid & 7;
    int b = bh >> 3, h = bh & 7;
    int w = threadIdx.x >> 6, lane = threadIdx.x & 63;
    int seg = oct * 16 + w;        // 0..127
    float run = pfx[((size_t)bh * NSEG2 + seg) * D_ + lane];
    const float* Vb = V + (size_t)bh * L_ * D_;
    int base = seg * SEG2;
    for (int l = 0; l < SEG2; ++l) {
      int gl = base + l;
      run += Vb[(size_t)gl * D_ + lane];
      out[(((size_t)b * L_ + gl) * H_ + h) * D_ + lane] = run;
    }
    return;
  }

  __shared__ unsigned keys[L_];    // 8 KB
  __shared__ int hist[256];
  __shared__ int Gs[256];
  __shared__ unsigned ctl_prefix;
  __shared__ int ctl_need, ctl_cnt, ctl_min;
  __shared__ int wmin[16];
  int bh = blockIdx.x;
  int tid = threadIdx.x;

  for (int i = tid; i < L_; i += 1024) {
    unsigned u = __float_as_uint(M[bh * L_ + i]);
    keys[i] = (u & 0x80000000u) ? ~u : (u | 0x80000000u);
  }
  if (tid == 0) { ctl_prefix = 0u; ctl_need = U_; ctl_cnt = 0; }
  __syncthreads();

  unsigned prefix = 0u, pmask = 0u;
#pragma unroll
  for (int pass = 0; pass < 4; ++pass) {
    int shift = 24 - 8 * pass;
    if (tid < 256) hist[tid] = 0;
    __syncthreads();
    for (int i = tid; i < L_; i += 1024) {
      unsigned k = keys[i];
      if ((k & pmask) == prefix) atomicAdd(&hist[(k >> shift) & 0xffu], 1);
    }
    __syncthreads();
    if (tid < 64) {
      int b0 = tid * 4;
      int h0 = hist[b0], h1 = hist[b0 + 1], h2 = hist[b0 + 2], h3 = hist[b0 + 3];
      int gs = h0 + h1 + h2 + h3;
      int S = gs;
#pragma unroll
      for (int d = 1; d < 64; d <<= 1) {
        int v = __shfl_down(S, d, 64);
        if (tid + d < 64) S += v;
      }
      int E = S - gs;
      Gs[b0 + 3] = E;
      Gs[b0 + 2] = E + h3;
      Gs[b0 + 1] = E + h3 + h2;
      Gs[b0 + 0] = E + h3 + h2 + h1;
    }
    __syncthreads();
    int need = ctl_need;
    if (tid < 256) {
      int G = Gs[tid], h = hist[tid];
      if (G < need && need <= G + h) {
        ctl_prefix = prefix | ((unsigned)tid << shift);
        ctl_need = need - G;
      }
    }
    __syncthreads();
    prefix = ctl_prefix;
    pmask |= (0xffu << shift);
  }

  unsigned v40 = prefix;
  int tiesNeeded = ctl_need;
  __syncthreads();

  for (int i = tid; i < L_; i += 1024) {
    if (keys[i] > v40) {
      int slot = atomicAdd(&ctl_cnt, 1);
      Mtop[bh * U_ + slot] = i;
    }
  }
  __syncthreads();
  int base = ctl_cnt;
  int last = -1;
  for (int t = 0; t < tiesNeeded; ++t) {
    int lmin = 0x7fffffff;
    for (int i = tid; i < L_; i += 1024)
      if (keys[i] == v40 && i > last) lmin = min(lmin, i);
#pragma unroll
    for (int d = 32; d > 0; d >>= 1) lmin = min(lmin, __shfl_xor(lmin, d, 64));
    if ((tid & 63) == 0) wmin[tid >> 6] = lmin;
    __syncthreads();
    if (tid == 0) {
      int m = wmin[0];
      for (int w = 1; w < 16; ++w) m = min(m, wmin[w]);
      Mtop[bh * U_ + base + t] = m;
      ctl_min = m;
    }
    __syncthreads();
    last = ctl_min;
  }
}

// ---------------------------------------------------------------------------
// Kernel 4a (v2): batched causal attention partials. 1280 blocks.
// ---------------------------------------------------------------------------
__global__ __launch_bounds__(256) void k_attn_part(
    const float* __restrict__ Q, const float* __restrict__ K,
    const float* __restrict__ V, const int* __restrict__ Mtop,
    float* __restrict__ pm, float* __restrict__ ps, float* __restrict__ pacc) {
  int blk = blockIdx.x;            // 0..1279
  int x = blk & 7;
  int j = blk >> 3;                // 0..159
  int bh = (j / 40) * 8 + x;
  int rem = j % 40;
  int c  = rem / NQG;              // K-chunk 0..7
  int qg = rem % NQG;              // query group 0..4

  int tid = threadIdx.x;
  int w = tid >> 6, lane = tid & 63;
  __shared__ float Qs[QG][D_];
  __shared__ float P[QG][CK];
  __shared__ float pvred[4][QG][D_];
  __shared__ int q0s[QG];
  if (tid < QG) q0s[tid] = Mtop[bh * U_ + qg * QG + tid];
  __syncthreads();
  for (int i = tid; i < QG * D_; i += 256) {
    int u = i >> 6, d = i & 63;
    Qs[u][d] = Q[((size_t)bh * L_ + q0s[u]) * D_ + d];
  }
  __syncthreads();

  int kg = c * CK + tid;
  const float4* kr = (const float4*)(K + ((size_t)bh * L_ + kg) * D_);
  float4 kv[16];
#pragma unroll
  for (int j4 = 0; j4 < 16; ++j4) kv[j4] = kr[j4];
#pragma unroll
  for (int u = 0; u < QG; ++u) {
    float acc = 0.f;
#pragma unroll
    for (int j4 = 0; j4 < 16; ++j4) {
      float4 qv = *(const float4*)&Qs[u][j4 * 4];
      acc += qv.x * kv[j4].x + qv.y * kv[j4].y + qv.z * kv[j4].z + qv.w * kv[j4].w;
    }
    P[u][tid] = (kg <= q0s[u]) ? acc : -INFINITY;
  }
  __syncthreads();

#pragma unroll
  for (int uu = 0; uu < 2; ++uu) {
    int u = w * 2 + uu;
    float v0 = P[u][lane], v1 = P[u][lane + 64];
    float v2 = P[u][lane + 128], v3 = P[u][lane + 192];
    float m = fmaxf(fmaxf(v0, v1), fmaxf(v2, v3));
    for (int o = 32; o > 0; o >>= 1) m = fmaxf(m, __shfl_xor(m, o, 64));
    float e0 = (v0 == -INFINITY) ? 0.f : expf(v0 - m);
    float e1 = (v1 == -INFINITY) ? 0.f : expf(v1 - m);
    float e2 = (v2 == -INFINITY) ? 0.f : expf(v2 - m);
    float e3 = (v3 == -INFINITY) ? 0.f : expf(v3 - m);
    float s = e0 + e1 + e2 + e3;
    for (int o = 32; o > 0; o >>= 1) s += __shfl_xor(s, o, 64);
    P[u][lane] = e0; P[u][lane + 64] = e1;
    P[u][lane + 128] = e2; P[u][lane + 192] = e3;
    if (lane == 0) {
      int p = (bh * NCHUNK + c) * U_ + qg * QG + u;
      pm[p] = m; ps[p] = s;
    }
  }
  __syncthreads();

  const float* Vb = V + ((size_t)bh * L_ + c * CK + w * 64) * D_;
  float acc[QG];
#pragma unroll
  for (int u = 0; u < QG; ++u) acc[u] = 0.f;
  for (int k4 = 0; k4 < 16; ++k4) {
    float4 pv[QG];
#pragma unroll
    for (int u = 0; u < QG; ++u) pv[u] = *(const float4*)&P[u][w * 64 + k4 * 4];
    float va = Vb[(size_t)(k4 * 4 + 0) * D_ + lane];
    float vb = Vb[(size_t)(k4 * 4 + 1) * D_ + lane];
    float vc = Vb[(size_t)(k4 * 4 + 2) * D_ + lane];
    float vd = Vb[(size_t)(k4 * 4 + 3) * D_ + lane];
#pragma unroll
    for (int u = 0; u < QG; ++u)
      acc[u] += pv[u].x * va + pv[u].y * vb + pv[u].z * vc + pv[u].w * vd;
  }
#pragma unroll
  for (int u = 0; u < QG; ++u) pvred[w][u][lane] = acc[u];
  __syncthreads();
#pragma unroll
  for (int uu = 0; uu < 2; ++uu) {
    int u = w * 2 + uu;
    float tot = pvred[0][u][lane] + pvred[1][u][lane] +
                pvred[2][u][lane] + pvred[3][u][lane];
    int p = (bh * NCHUNK + c) * U_ + qg * QG + u;
    pacc[(size_t)p * 64 + lane] = tot;
  }
}

// ---------------------------------------------------------------------------
// Kernel 4b: merge chunk partials, normalize, scatter into out.
// ---------------------------------------------------------------------------
__global__ __launch_bounds__(256) void k_attn_reduce(
    const float* __restrict__ pm, const float* __restrict__ ps,
    const float* __restrict__ pacc, const int* __restrict__ Mtop,
    float* __restrict__ out) {
  int g = blockIdx.x * 4 + (threadIdx.x >> 6);
  int lane = threadIdx.x & 63;
  int bh = g / U_, u = g % U_;
  int b = bh >> 3, h = bh & 7;
  int q0 = Mtop[bh * U_ + u];
  float pmv[NCHUNK];
  float M = -INFINITY;
#pragma unroll
  for (int c = 0; c < NCHUNK; ++c) {
    pmv[c] = pm[(bh * NCHUNK + c) * U_ + u];
    M = fmaxf(M, pmv[c]);
  }
  float T = 0.f, o = 0.f;
#pragma unroll
  for (int c = 0; c < NCHUNK; ++c) {
    float wgt = (pmv[c] == -INFINITY) ? 0.f : expf(pmv[c] - M);
    T += ps[(bh * NCHUNK + c) * U_ + u] * wgt;
    o += pacc[((size_t)(bh * NCHUNK + c) * U_ + u) * 64 + lane] * wgt;
  }
  out[(((size_t)b * L_ + q0) * H_ + h) * D_ + lane] = o / T;
}

extern "C" void kernel_launch(void* const* d_in, const int* in_sizes, int n_in,
                              void* d_out, int out_size, void* d_ws, size_t ws_size,
                              hipStream_t stream) {
  const float* Q = (const float*)d_in[0];
  const float* K = (const float*)d_in[1];
  const float* V = (const float*)d_in[2];
  const int* idxs = (const int*)d_in[3];
  float* out = (float*)d_out;

  char* ws = (char*)d_ws;
  float* M    = (float*)(ws + 0);              // 256 KB
  float* pfx  = (float*)(ws + 262144);         // 1 MB
  int*   Mtop = (int*)(ws + 1310720);          // 5 KB (pad to 8 KB)
  float* pm   = (float*)(ws + 1318912);        // 40 KB
  float* ps   = (float*)(ws + 1359872);        // 40 KB
  float* pacc = (float*)(ws + 1400832);        // 2.62 MB
  unsigned short* list = (unsigned short*)(ws + 4022272);  // 640 KB

  // allow 128KB dynamic LDS for the staged-M kernel (idempotent host call)
  (void)hipFuncSetAttribute((const void*)k_compute_M,
                            hipFuncAttributeMaxDynamicSharedMemorySize, 131072);

  // 0) setup: idx chunk-sort (blocks 0..7) + cumsum phase A (blocks 8..39)
  k_setup<<<SORTB + 32, 256, 0, stream>>>(idxs, V, list, pfx);
  // 1) LDS-staged M scores (256 blocks, 128KB LDS each)
  k_compute_M<<<256, 256, 131072, stream>>>(Q, K, list, M);
  // 2) fused: top-k (blocks 0..31) + cumsum phase B (blocks 32..287)
  k_topk<<<CSB + PB, 1024, 0, stream>>>(M, V, pfx, Mtop, out);
  // 3) batched causal attention partials
  k_attn_part<<<B_ * H_ * NCHUNK * NQG, 256, 0, stream>>>(Q, K, V, Mtop, pm, ps, pacc);
  // 4) merge partials, overwrite selected rows
  k_attn_reduce<<<(B_ * H_ * U_) / 4, 256, 0, stream>>>(pm, ps, pacc, Mtop, out);
}